// Round 1
// baseline (3097.509 us; speedup 1.0000x reference)
//
#include <hip/hip_runtime.h>
#include <math.h>

#define TT   1024   // T
#define BBZ  4      // B
#define DD   512    // D
#define DFF_ 2048
#define HH   8
#define DKK  64
#define PP   2047   // 2T-1
#define NTOK 4096   // B*T
#define EPSF 1e-5f

__device__ __forceinline__ float sigmoidf_(float x){ return 1.0f/(1.0f+__expf(-x)); }

// ---------------- LayerNorm: one block per row of 512 ----------------
__global__ __launch_bounds__(256) void ln_kernel(const float* __restrict__ in,
    const float* __restrict__ g, const float* __restrict__ b,
    float* __restrict__ out)
{
    int row = blockIdx.x;
    int t = threadIdx.x;
    const float* x = in + (size_t)row*DD;
    float v0 = x[t], v1 = x[t+256];
    __shared__ float rs[256], rq[256];
    rs[t] = v0+v1; rq[t] = v0*v0+v1*v1;
    __syncthreads();
    for (int st=128; st>0; st>>=1){
        if (t<st){ rs[t]+=rs[t+st]; rq[t]+=rq[t+st]; }
        __syncthreads();
    }
    float mean = rs[0]*(1.0f/DD);
    float var  = rq[0]*(1.0f/DD) - mean*mean;
    float inv  = rsqrtf(var+EPSF);
    out[(size_t)row*DD+t]     = (v0-mean)*inv*g[t]     + b[t];
    out[(size_t)row*DD+t+256] = (v1-mean)*inv*g[t+256] + b[t+256];
}

// ---------------- generic f32 GEMM, 64x64 tile, 4x4 per thread ----------------
// C[M,N] = epilogue(A[M,Kd] @ B)   B: (Kd,N) if TRANSB==0, (N,Kd) if TRANSB==1
// epilogue: vv = acc (+bias[n]); if act==1 vv=silu(vv); vv*=alpha; (+resid[m,n])
template<int TRANSB>
__global__ __launch_bounds__(256) void gemm_kernel(
    const float* __restrict__ A, int lda,
    const float* __restrict__ Bm, int ldb,
    float* __restrict__ C, int ldc,
    int M, int N, int Kd,
    const float* __restrict__ bias, int act, float alpha,
    const float* __restrict__ resid)
{
    __shared__ float As[16][65];
    __shared__ float Bs[16][65];
    int m0 = blockIdx.y*64, n0 = blockIdx.x*64;
    int t = threadIdx.x;
    int tr = t>>4, tc = t&15;
    float acc[4][4] = {};
    for (int k0=0; k0<Kd; k0+=16){
        for (int e=t; e<1024; e+=256){
            int m = e>>4, kk = e&15;
            int gm = m0+m;
            As[kk][m] = (gm<M) ? A[(size_t)gm*lda + k0+kk] : 0.0f;
        }
        if (TRANSB){
            for (int e=t; e<1024; e+=256){
                int n = e>>4, kk = e&15;
                int gn = n0+n;
                Bs[kk][n] = (gn<N) ? Bm[(size_t)gn*ldb + k0+kk] : 0.0f;
            }
        } else {
            for (int e=t; e<1024; e+=256){
                int n = e&63, kk = e>>6;
                int gn = n0+n;
                Bs[kk][n] = (gn<N) ? Bm[(size_t)(k0+kk)*ldb + gn] : 0.0f;
            }
        }
        __syncthreads();
        #pragma unroll
        for (int kk=0; kk<16; kk++){
            float a[4], bb[4];
            #pragma unroll
            for (int i=0;i<4;i++) a[i]  = As[kk][tr+16*i];
            #pragma unroll
            for (int j=0;j<4;j++) bb[j] = Bs[kk][tc+16*j];
            #pragma unroll
            for (int i=0;i<4;i++)
                #pragma unroll
                for (int j=0;j<4;j++)
                    acc[i][j] = fmaf(a[i], bb[j], acc[i][j]);
        }
        __syncthreads();
    }
    #pragma unroll
    for (int i=0;i<4;i++){
        int gm = m0+tr+16*i;
        if (gm>=M) continue;
        #pragma unroll
        for (int j=0;j<4;j++){
            int gn = n0+tc+16*j;
            if (gn>=N) continue;
            float vv = acc[i][j];
            if (bias)  vv += bias[gn];
            if (act==1) vv = vv*sigmoidf_(vv);
            vv *= alpha;
            if (resid) vv += resid[(size_t)gm*ldc + gn];
            C[(size_t)gm*ldc + gn] = vv;
        }
    }
}

// ---------------- attention scores: (q+u)�k + (q+v)�p[j+T-1-i], *0.125 ----------------
// one block -> 32x32 score tile for head h of batch b; scores layout (H,T,T)
__global__ __launch_bounds__(256) void score_kernel(
    const float* __restrict__ q, const float* __restrict__ k,
    const float* __restrict__ p,
    const float* __restrict__ pos_u, const float* __restrict__ pos_v,
    float* __restrict__ scores, int b)
{
    int h = blockIdx.z;
    int i0 = blockIdx.y*32, j0 = blockIdx.x*32;
    __shared__ float qu[32][65], qv[32][65], kt[32][65], pb[63][65];
    int t = threadIdx.x;
    for (int e=t; e<32*64; e+=256){
        int r = e>>6, d = e&63;
        float qq = q[(size_t)(b*TT+i0+r)*DD + h*DKK + d];
        qu[r][d] = qq + pos_u[h*DKK+d];
        qv[r][d] = qq + pos_v[h*DKK+d];
        kt[r][d] = k[(size_t)(b*TT+j0+r)*DD + h*DKK + d];
    }
    int jjbase = j0 + (TT-1) - i0 - 31;   // always in [0, 2046-62]
    for (int e=t; e<63*64; e+=256){
        int r = e>>6, d = e&63;
        pb[r][d] = p[(size_t)(jjbase+r)*DD + h*DKK + d];
    }
    __syncthreads();
    int ii = t>>3, jb = (t&7)*4;
    float s[4] = {0.f,0.f,0.f,0.f};
    #pragma unroll 8
    for (int d=0; d<64; d++){
        float a  = qu[ii][d];
        float vq = qv[ii][d];
        #pragma unroll
        for (int e2=0;e2<4;e2++){
            int jj = jb+e2;
            s[e2] += a*kt[jj][d] + vq*pb[31+jj-ii][d];
        }
    }
    float* srow = scores + ((size_t)h*TT + i0+ii)*TT + j0 + jb;
    #pragma unroll
    for (int e2=0;e2<4;e2++) srow[e2] = s[e2]*0.125f;
}

// ---------------- softmax over rows of 1024 ----------------
__global__ __launch_bounds__(256) void softmax_kernel(float* __restrict__ s)
{
    size_t row = blockIdx.x;
    float* x = s + row*TT;
    int t = threadIdx.x;
    float v[4];
    float mx = -1e30f;
    #pragma unroll
    for (int e=0;e<4;e++){ v[e] = x[t+256*e]; mx = fmaxf(mx, v[e]); }
    __shared__ float red[256];
    red[t] = mx; __syncthreads();
    for (int st=128; st>0; st>>=1){
        if (t<st) red[t] = fmaxf(red[t], red[t+st]);
        __syncthreads();
    }
    mx = red[0];
    __syncthreads();
    float sum = 0.f;
    #pragma unroll
    for (int e=0;e<4;e++){ v[e] = __expf(v[e]-mx); sum += v[e]; }
    red[t] = sum; __syncthreads();
    for (int st=128; st>0; st>>=1){
        if (t<st) red[t] += red[t+st];
        __syncthreads();
    }
    float inv = 1.0f/red[0];
    #pragma unroll
    for (int e=0;e<4;e++) x[t+256*e] = v[e]*inv;
}

// ---------------- attn @ v: per (b,h), 64 rows x DK=64 per block ----------------
__global__ __launch_bounds__(256) void attnv_kernel(
    const float* __restrict__ scores, const float* __restrict__ v,
    float* __restrict__ out, int b)
{
    int h = blockIdx.y;
    int i0 = blockIdx.x*64;
    __shared__ float Ps[32][65], Vs[32][65];
    int t = threadIdx.x;
    int tr = t>>4, tc = t&15;
    float acc[4][4] = {};
    for (int k0=0; k0<TT; k0+=32){
        for (int e=t; e<2048; e+=256){
            int m = e>>5, kk = e&31;
            Ps[kk][m] = scores[((size_t)h*TT + i0+m)*TT + k0+kk];
        }
        for (int e=t; e<2048; e+=256){
            int kk = e>>6, d = e&63;
            Vs[kk][d] = v[(size_t)(b*TT+k0+kk)*DD + h*DKK + d];
        }
        __syncthreads();
        #pragma unroll
        for (int kk=0; kk<32; kk++){
            float a[4], bb[4];
            #pragma unroll
            for (int i=0;i<4;i++) a[i]  = Ps[kk][tr+16*i];
            #pragma unroll
            for (int j=0;j<4;j++) bb[j] = Vs[kk][tc+16*j];
            #pragma unroll
            for (int i=0;i<4;i++)
                #pragma unroll
                for (int j=0;j<4;j++)
                    acc[i][j] = fmaf(a[i], bb[j], acc[i][j]);
        }
        __syncthreads();
    }
    #pragma unroll
    for (int i=0;i<4;i++)
        #pragma unroll
        for (int j=0;j<4;j++)
            out[(size_t)(b*TT+i0+tr+16*i)*DD + h*DKK + tc+16*j] = acc[i][j];
}

// ---------------- GLU: a * sigmoid(g), channels split ----------------
__global__ __launch_bounds__(256) void glu_kernel(const float* __restrict__ in, float* __restrict__ out)
{
    int idx = blockIdx.x*256 + threadIdx.x;   // over NTOK*DD
    int r = idx >> 9, c = idx & 511;
    float a  = in[(size_t)r*1024 + c];
    float gg = in[(size_t)r*1024 + 512 + c];
    out[idx] = a * sigmoidf_(gg);
}

// ---------------- depthwise conv K=31, pad 15, per-batch boundaries ----------------
__global__ __launch_bounds__(256) void dwconv_kernel(
    const float* __restrict__ y, const float* __restrict__ w,
    const float* __restrict__ bias, float* __restrict__ z)
{
    int idx = blockIdx.x*256 + threadIdx.x;   // over NTOK*DD
    int d   = idx & (DD-1);
    int bt  = idx >> 9;
    int b   = bt >> 10;
    int tp0 = bt & (TT-1);
    float s = bias[d];
    #pragma unroll
    for (int kk=0; kk<31; kk++){
        int tp = tp0 - 15 + kk;
        if (tp >= 0 && tp < TT)
            s = fmaf(y[(size_t)(b*TT+tp)*DD + d], w[d*31+kk], s);
    }
    z[idx] = s;
}

// ---------------- BN stats: one block per channel, sum + sumsq over 4096 ----------------
__global__ __launch_bounds__(256) void bn_reduce_kernel(const float* __restrict__ z, float* __restrict__ stats)
{
    int c = blockIdx.x;
    int t = threadIdx.x;
    float s=0.f, q=0.f;
    for (int r=t; r<NTOK; r+=256){
        float vv = z[(size_t)r*DD + c];
        s += vv; q += vv*vv;
    }
    __shared__ float rs[256], rq[256];
    rs[t]=s; rq[t]=q; __syncthreads();
    for (int st=128; st>0; st>>=1){
        if (t<st){ rs[t]+=rs[t+st]; rq[t]+=rq[t+st]; }
        __syncthreads();
    }
    if (t==0){ stats[c]=rs[0]; stats[DD+c]=rq[0]; }
}

// ---------------- BN apply + SiLU ----------------
__global__ __launch_bounds__(256) void bn_apply_kernel(
    const float* __restrict__ z, const float* __restrict__ stats,
    const float* __restrict__ g, const float* __restrict__ b,
    float* __restrict__ out)
{
    int idx = blockIdx.x*256 + threadIdx.x;   // NTOK*DD
    int c = idx & (DD-1);
    float m   = stats[c]*(1.0f/NTOK);
    float var = stats[DD+c]*(1.0f/NTOK) - m*m;
    float vv  = (z[idx]-m)*rsqrtf(var+EPSF)*g[c] + b[c];
    out[idx]  = vv*sigmoidf_(vv);
}

extern "C" void kernel_launch(void* const* d_in, const int* in_sizes, int n_in,
                              void* d_out, int out_size, void* d_ws, size_t ws_size,
                              hipStream_t stream)
{
    const float* x       = (const float*)d_in[0];
    const float* pos_emb = (const float*)d_in[1];
    const float* ln1_g=(const float*)d_in[2],  *ln1_b=(const float*)d_in[3];
    const float* ln2_g=(const float*)d_in[4],  *ln2_b=(const float*)d_in[5];
    const float* ln3_g=(const float*)d_in[6],  *ln3_b=(const float*)d_in[7];
    const float* ln4_g=(const float*)d_in[8],  *ln4_b=(const float*)d_in[9];
    const float* ln5_g=(const float*)d_in[10], *ln5_b=(const float*)d_in[11];
    const float* ff1_w1=(const float*)d_in[12], *ff1_b1=(const float*)d_in[13];
    const float* ff1_w2=(const float*)d_in[14], *ff1_b2=(const float*)d_in[15];
    const float* wq=(const float*)d_in[16], *bq=(const float*)d_in[17];
    const float* wk=(const float*)d_in[18], *bk=(const float*)d_in[19];
    const float* wv=(const float*)d_in[20], *bv=(const float*)d_in[21];
    const float* wp=(const float*)d_in[22];
    const float* wo=(const float*)d_in[23], *bo=(const float*)d_in[24];
    const float* pos_u=(const float*)d_in[25], *pos_v=(const float*)d_in[26];
    const float* pw1_w=(const float*)d_in[27], *pw1_b=(const float*)d_in[28];
    const float* dw_w=(const float*)d_in[29],  *dw_b=(const float*)d_in[30];
    const float* bn_g=(const float*)d_in[31],  *bn_b=(const float*)d_in[32];
    const float* pw2_w=(const float*)d_in[33], *pw2_b=(const float*)d_in[34];
    const float* ff2_w1=(const float*)d_in[35], *ff2_b1=(const float*)d_in[36];
    const float* ff2_w2=(const float*)d_in[37], *ff2_b2=(const float*)d_in[38];

    float* ws   = (float*)d_ws;
    float* h    = ws;                 // 4096*512
    float* xn   = ws +  2097152;      // 4096*512
    float* ffh  = ws +  4194304;      // 4096*2048 == 8*1024*1024 (reused as per-batch scores)
    float* q    = ws + 12582912;      // 4096*512
    float* k    = ws + 14680064;      // 4096*512
    float* v    = ws + 16777216;      // 4096*512
    float* p    = ws + 18874368;      // 2047*512
    float* t1   = ws + 19922944;      // 4096*512
    float* t2   = ws + 22020096;      // 4096*1024
    float* t3   = ws + 26214400;      // 4096*512
    float* stats= ws + 28311552;      // 1024

    dim3 blk(256);

    // ---- FFN1: h = x + 0.5*ffn(ln1(x)) ----
    ln_kernel<<<dim3(NTOK), blk, 0, stream>>>(x, ln1_g, ln1_b, xn);
    gemm_kernel<0><<<dim3(DFF_/64, NTOK/64), blk, 0, stream>>>(
        xn, DD, ff1_w1, DFF_, ffh, DFF_, NTOK, DFF_, DD, ff1_b1, 1, 1.0f, nullptr);
    gemm_kernel<0><<<dim3(DD/64, NTOK/64), blk, 0, stream>>>(
        ffh, DFF_, ff1_w2, DD, h, DD, NTOK, DD, DFF_, ff1_b2, 0, 0.5f, x);

    // ---- Attention: h = h + attn(ln2(h)) ----
    ln_kernel<<<dim3(NTOK), blk, 0, stream>>>(h, ln2_g, ln2_b, xn);
    gemm_kernel<0><<<dim3(DD/64, NTOK/64), blk, 0, stream>>>(
        xn, DD, wq, DD, q, DD, NTOK, DD, DD, bq, 0, 1.0f, nullptr);
    gemm_kernel<0><<<dim3(DD/64, NTOK/64), blk, 0, stream>>>(
        xn, DD, wk, DD, k, DD, NTOK, DD, DD, bk, 0, 1.0f, nullptr);
    gemm_kernel<0><<<dim3(DD/64, NTOK/64), blk, 0, stream>>>(
        xn, DD, wv, DD, v, DD, NTOK, DD, DD, bv, 0, 1.0f, nullptr);
    gemm_kernel<0><<<dim3(DD/64, (PP+63)/64), blk, 0, stream>>>(
        pos_emb, DD, wp, DD, p, DD, PP, DD, DD, nullptr, 0, 1.0f, nullptr);

    for (int b=0; b<BBZ; b++){
        score_kernel<<<dim3(TT/32, TT/32, HH), blk, 0, stream>>>(q, k, p, pos_u, pos_v, ffh, b);
        softmax_kernel<<<dim3(HH*TT), blk, 0, stream>>>(ffh);
        attnv_kernel<<<dim3(TT/64, HH), blk, 0, stream>>>(ffh, v, t1, b);
    }
    gemm_kernel<0><<<dim3(DD/64, NTOK/64), blk, 0, stream>>>(
        t1, DD, wo, DD, h, DD, NTOK, DD, DD, bo, 0, 1.0f, h);

    // ---- Conv module: h = h + conv(ln3(h)) ----
    ln_kernel<<<dim3(NTOK), blk, 0, stream>>>(h, ln3_g, ln3_b, xn);
    gemm_kernel<1><<<dim3(1024/64, NTOK/64), blk, 0, stream>>>(
        xn, DD, pw1_w, DD, t2, 1024, NTOK, 1024, DD, pw1_b, 0, 1.0f, nullptr);
    glu_kernel<<<dim3(NTOK*DD/256), blk, 0, stream>>>(t2, t1);
    dwconv_kernel<<<dim3(NTOK*DD/256), blk, 0, stream>>>(t1, dw_w, dw_b, t3);
    bn_reduce_kernel<<<dim3(DD), blk, 0, stream>>>(t3, stats);
    bn_apply_kernel<<<dim3(NTOK*DD/256), blk, 0, stream>>>(t3, stats, bn_g, bn_b, t1);
    gemm_kernel<1><<<dim3(DD/64, NTOK/64), blk, 0, stream>>>(
        t1, DD, pw2_w, DD, h, DD, NTOK, DD, DD, pw2_b, 0, 1.0f, h);

    // ---- FFN2: h = h + 0.5*ffn(ln4(h)) ----
    ln_kernel<<<dim3(NTOK), blk, 0, stream>>>(h, ln4_g, ln4_b, xn);
    gemm_kernel<0><<<dim3(DFF_/64, NTOK/64), blk, 0, stream>>>(
        xn, DD, ff2_w1, DFF_, ffh, DFF_, NTOK, DFF_, DD, ff2_b1, 1, 1.0f, nullptr);
    gemm_kernel<0><<<dim3(DD/64, NTOK/64), blk, 0, stream>>>(
        ffh, DFF_, ff2_w2, DD, h, DD, NTOK, DD, DFF_, ff2_b2, 0, 0.5f, h);

    // ---- Final LN ----
    ln_kernel<<<dim3(NTOK), blk, 0, stream>>>(h, ln5_g, ln5_b, (float*)d_out);
}

// Round 2
// 544.837 us; speedup vs baseline: 5.6852x; 5.6852x over previous
//
#include <hip/hip_runtime.h>
#include <math.h>

#define TT   1024
#define BBZ  4
#define DD   512
#define DFF_ 2048
#define HH   8
#define DKK  64
#define NTOK 4096
#define EPSF 1e-5f
#define MB   1048576

typedef unsigned short u16;
typedef __attribute__((ext_vector_type(8))) short s8v;    // 8 bf16 (4 VGPRs)
typedef __attribute__((ext_vector_type(4))) float f32x4;

__device__ __forceinline__ float b2f(u16 v){
    union { unsigned int u; float f; } x; x.u = ((unsigned int)v) << 16; return x.f;
}
__device__ __forceinline__ u16 f2b(float f){
    union { float f; unsigned int u; } x; x.f = f;
    unsigned int r = x.u + 0x7fffu + ((x.u >> 16) & 1u);
    return (u16)(r >> 16);
}
__device__ __forceinline__ float sigmoidf_(float x){ return 1.0f/(1.0f+__expf(-x)); }

__device__ __forceinline__ void gld16(const u16* g, u16* l){
    __builtin_amdgcn_global_load_lds(
        (const __attribute__((address_space(1))) unsigned int*)g,
        (__attribute__((address_space(3))) unsigned int*)l, 16, 0, 0);
}

// ================= batched MFMA GEMM =================
// C = epilogue(A @ B^T_view), A:(M,K) bf16 row-major, B:(N,K) bf16 row-major.
// z-batched: zb=z>>3, zh=z&7; per-operand offsets off = zb*s_b + zh*s_h (elements).
// OMODE 0: f32 out (+bias, act, *alpha, +resid)   1: bf16 out (+bias, act)
// OMODE 2: bf16 V-transposed store                 3: bf16 dual (q+u),(q+v) store
// OMODE 4: bf16 rel-shifted store (band)
template<int OMODE>
__global__ __launch_bounds__(256) void bgemm(
    const u16* __restrict__ A, int lda, long sAb, long sAh,
    const u16* __restrict__ B, int ldb, long sBb, long sBh,
    void* __restrict__ Cv, int ldc, long sCb, long sCh,
    int M, int N, int K,
    const float* __restrict__ bias, int act, float alpha,
    const float* __restrict__ resid,
    const float* __restrict__ posu, const float* __restrict__ posv,
    u16* __restrict__ out2, int band)
{
    int z  = blockIdx.z;
    int zb = z >> 3, zh = z & 7;
    int n0 = blockIdx.x * 64;
    int m0 = blockIdx.y * 128;
    if (OMODE == 4 && band){
        // needed r range for rows [m0, m0+127]: [896-m0, 2046-m0]
        if (n0 + 63 < 896 - m0 || n0 > 2046 - m0) return;
    }
    const u16* Ab = A + (size_t)zb*sAb + (size_t)zh*sAh;
    const u16* Bb = B + (size_t)zb*sBb + (size_t)zh*sBh;

    __shared__ u16 As[128*64];
    __shared__ u16 Bs[64*64];

    int t = threadIdx.x;
    int w = t >> 6, l = t & 63;
    int lrow = l >> 3, lslot = l & 7;
    int kswz = (lslot ^ lrow) * 8;          // pre-swizzled global k-offset (elems)
    int wm = w >> 1, wn = w & 1;
    int lr = l & 15, lk = l >> 4;

    f32x4 acc[4][2] = {};

    for (int k0 = 0; k0 < K; k0 += 64){
        #pragma unroll
        for (int it = 0; it < 4; ++it){
            int rb = it*32 + w*8;
            gld16(Ab + (size_t)(m0 + rb + lrow)*lda + k0 + kswz, &As[rb*64]);
        }
        #pragma unroll
        for (int it = 0; it < 2; ++it){
            int rb = it*32 + w*8;
            gld16(Bb + (size_t)(n0 + rb + lrow)*ldb + k0 + kswz, &Bs[rb*64]);
        }
        __syncthreads();

        s8v af[2][4], bf[2][2];
        #pragma unroll
        for (int kh = 0; kh < 2; ++kh){
            #pragma unroll
            for (int mi = 0; mi < 4; ++mi){
                int row = wm*64 + mi*16 + lr;
                int sl  = (kh*4 + lk) ^ (lr & 7);
                af[kh][mi] = *(const s8v*)&As[row*64 + sl*8];
            }
            #pragma unroll
            for (int ni = 0; ni < 2; ++ni){
                int row = wn*32 + ni*16 + lr;
                int sl  = (kh*4 + lk) ^ (lr & 7);
                bf[kh][ni] = *(const s8v*)&Bs[row*64 + sl*8];
            }
        }
        #pragma unroll
        for (int kh = 0; kh < 2; ++kh)
            #pragma unroll
            for (int mi = 0; mi < 4; ++mi)
                #pragma unroll
                for (int ni = 0; ni < 2; ++ni)
                    acc[mi][ni] = __builtin_amdgcn_mfma_f32_16x16x32_bf16(
                        af[kh][mi], bf[kh][ni], acc[mi][ni], 0, 0, 0);
        __syncthreads();
    }

    // epilogue: C row = m (A side), col = n (B side); col=lane&15, row=(lane>>4)*4+r
    #pragma unroll
    for (int mi = 0; mi < 4; ++mi){
        #pragma unroll
        for (int ni = 0; ni < 2; ++ni){
            int gn = n0 + wn*32 + ni*16 + lr;
            float bval = (OMODE == 4) ? 0.0f : (bias ? bias[gn] : 0.0f);
            #pragma unroll
            for (int r = 0; r < 4; ++r){
                int gm = m0 + wm*64 + mi*16 + lk*4 + r;
                float vv = acc[mi][ni][r] + bval;
                if (act) vv = vv * sigmoidf_(vv);
                if (OMODE == 0){
                    vv *= alpha;
                    if (resid) vv += resid[(size_t)gm*ldc + gn];
                    ((float*)Cv)[(size_t)zb*sCb + (size_t)zh*sCh + (size_t)gm*ldc + gn] = vv;
                } else if (OMODE == 1){
                    ((u16*)Cv)[(size_t)zb*sCb + (size_t)zh*sCh + (size_t)gm*ldc + gn] = f2b(vv);
                } else if (OMODE == 2){
                    int bb = gm >> 10, tt2 = gm & 1023;
                    size_t idx = (((size_t)(bb*8 + (gn>>6)))*64 + (gn&63))*1024 + tt2;
                    ((u16*)Cv)[idx] = f2b(vv);
                } else if (OMODE == 3){
                    size_t idx = (size_t)gm*ldc + gn;
                    ((u16*)Cv)[idx] = f2b(vv + posu[gn]);
                    out2[idx]       = f2b(vv + posv[gn]);
                } else { // 4: rel-shifted bd store
                    int j = gn - 1023 + gm;
                    if (j >= 0 && j < 1024)
                        ((u16*)Cv)[(size_t)zb*sCb + (size_t)zh*sCh + (size_t)gm*1024 + j] = f2b(vv);
                }
            }
        }
    }
}

// ================= LayerNorm (f32 in, bf16/f32 out) =================
template<int OB>
__global__ __launch_bounds__(256) void ln_kernel(const float* __restrict__ in,
    const float* __restrict__ g, const float* __restrict__ b, void* __restrict__ outv)
{
    int row = blockIdx.x, t = threadIdx.x;
    const float* x = in + (size_t)row*DD;
    float v0 = x[t], v1 = x[t+256];
    __shared__ float rs[256], rq[256];
    rs[t] = v0+v1; rq[t] = v0*v0+v1*v1;
    __syncthreads();
    for (int st=128; st>0; st>>=1){
        if (t<st){ rs[t]+=rs[t+st]; rq[t]+=rq[t+st]; }
        __syncthreads();
    }
    float mean = rs[0]*(1.0f/DD);
    float var  = rq[0]*(1.0f/DD) - mean*mean;
    float inv  = rsqrtf(var+EPSF);
    float y0 = (v0-mean)*inv*g[t]     + b[t];
    float y1 = (v1-mean)*inv*g[t+256] + b[t+256];
    if (OB){
        u16* o = (u16*)outv;
        o[(size_t)row*DD+t] = f2b(y0); o[(size_t)row*DD+t+256] = f2b(y1);
    } else {
        float* o = (float*)outv;
        o[(size_t)row*DD+t] = y0; o[(size_t)row*DD+t+256] = y1;
    }
}

// ================= weight prep =================
__global__ __launch_bounds__(256) void transpose_bf16(const float* __restrict__ in,
    u16* __restrict__ out, int R, int C)
{
    __shared__ float tile[32][33];
    int c0 = blockIdx.x*32, r0 = blockIdx.y*32;
    int tx = threadIdx.x & 31, ty = threadIdx.x >> 5;
    #pragma unroll
    for (int i=0;i<4;i++){
        int rr = ty + i*8;
        tile[rr][tx] = in[(size_t)(r0+rr)*C + c0+tx];
    }
    __syncthreads();
    #pragma unroll
    for (int i=0;i<4;i++){
        int cc = ty + i*8;
        out[(size_t)(c0+cc)*R + r0+tx] = f2b(tile[tx][cc]);
    }
}

__global__ __launch_bounds__(256) void convert_pad(const float* __restrict__ in,
    u16* __restrict__ out, int nin, int nout)
{
    int i = blockIdx.x*256 + threadIdx.x;
    if (i < nout) out[i] = (i < nin) ? f2b(in[i]) : (u16)0;
}

// ================= softmax over (ac + shifted-bd)*0.125, in-place bf16 =================
__global__ __launch_bounds__(256) void shift_softmax_kernel(u16* __restrict__ ac,
    const u16* __restrict__ bdsh)
{
    int i = blockIdx.x, z = blockIdx.y;
    size_t base = ((size_t)z*1024 + i)*1024;
    int t = threadIdx.x;
    float s[4]; float mx = -1e30f;
    #pragma unroll
    for (int e=0;e<4;e++){
        int c = t + 256*e;
        s[e] = (b2f(ac[base+c]) + b2f(bdsh[base+c]))*0.125f;
        mx = fmaxf(mx, s[e]);
    }
    __shared__ float red[256];
    red[t]=mx; __syncthreads();
    for (int st=128; st>0; st>>=1){ if(t<st) red[t]=fmaxf(red[t],red[t+st]); __syncthreads(); }
    mx = red[0]; __syncthreads();
    float sum = 0.f;
    #pragma unroll
    for (int e=0;e<4;e++){ s[e]=__expf(s[e]-mx); sum+=s[e]; }
    red[t]=sum; __syncthreads();
    for (int st=128; st>0; st>>=1){ if(t<st) red[t]+=red[t+st]; __syncthreads(); }
    float inv = 1.0f/red[0];
    #pragma unroll
    for (int e=0;e<4;e++) ac[base + t + 256*e] = f2b(s[e]*inv);
}

// ================= conv-module elementwise =================
__global__ __launch_bounds__(256) void glu_kernel(const float* __restrict__ in, u16* __restrict__ out)
{
    int idx = blockIdx.x*256 + threadIdx.x;
    int r = idx >> 9, c = idx & 511;
    float a  = in[(size_t)r*1024 + c];
    float gg = in[(size_t)r*1024 + 512 + c];
    out[idx] = f2b(a * sigmoidf_(gg));
}

__global__ __launch_bounds__(256) void dwconv_kernel(const u16* __restrict__ y,
    const float* __restrict__ w, const float* __restrict__ bias, float* __restrict__ z)
{
    int idx = blockIdx.x*256 + threadIdx.x;
    int d   = idx & (DD-1);
    int bt  = idx >> 9;
    int b   = bt >> 10;
    int tp0 = bt & (TT-1);
    float s = bias[d];
    #pragma unroll
    for (int kk=0; kk<31; kk++){
        int tp = tp0 - 15 + kk;
        if (tp >= 0 && tp < TT)
            s = fmaf(b2f(y[(size_t)(b*TT+tp)*DD + d]), w[d*31+kk], s);
    }
    z[idx] = s;
}

__global__ __launch_bounds__(256) void bn_reduce_kernel(const float* __restrict__ z, float* __restrict__ stats)
{
    int c = blockIdx.x, t = threadIdx.x;
    float s=0.f, q=0.f;
    for (int r=t; r<NTOK; r+=256){
        float vv = z[(size_t)r*DD + c];
        s += vv; q += vv*vv;
    }
    __shared__ float rs[256], rq[256];
    rs[t]=s; rq[t]=q; __syncthreads();
    for (int st=128; st>0; st>>=1){
        if (t<st){ rs[t]+=rs[t+st]; rq[t]+=rq[t+st]; }
        __syncthreads();
    }
    if (t==0){ stats[c]=rs[0]; stats[DD+c]=rq[0]; }
}

__global__ __launch_bounds__(256) void bn_apply_kernel(const float* __restrict__ z,
    const float* __restrict__ stats, const float* __restrict__ g, const float* __restrict__ b,
    u16* __restrict__ out)
{
    int idx = blockIdx.x*256 + threadIdx.x;
    int c = idx & (DD-1);
    float m   = stats[c]*(1.0f/NTOK);
    float var = stats[DD+c]*(1.0f/NTOK) - m*m;
    float vv  = (z[idx]-m)*rsqrtf(var+EPSF)*g[c] + b[c];
    out[idx]  = f2b(vv*sigmoidf_(vv));
}

extern "C" void kernel_launch(void* const* d_in, const int* in_sizes, int n_in,
                              void* d_out, int out_size, void* d_ws, size_t ws_size,
                              hipStream_t stream)
{
    const float* x       = (const float*)d_in[0];
    const float* pos_emb = (const float*)d_in[1];
    const float* ln1_g=(const float*)d_in[2],  *ln1_b=(const float*)d_in[3];
    const float* ln2_g=(const float*)d_in[4],  *ln2_b=(const float*)d_in[5];
    const float* ln3_g=(const float*)d_in[6],  *ln3_b=(const float*)d_in[7];
    const float* ln4_g=(const float*)d_in[8],  *ln4_b=(const float*)d_in[9];
    const float* ln5_g=(const float*)d_in[10], *ln5_b=(const float*)d_in[11];
    const float* ff1_w1=(const float*)d_in[12], *ff1_b1=(const float*)d_in[13];
    const float* ff1_w2=(const float*)d_in[14], *ff1_b2=(const float*)d_in[15];
    const float* wq=(const float*)d_in[16], *bq=(const float*)d_in[17];
    const float* wk=(const float*)d_in[18], *bk=(const float*)d_in[19];
    const float* wv=(const float*)d_in[20], *bv=(const float*)d_in[21];
    const float* wp=(const float*)d_in[22];
    const float* wo=(const float*)d_in[23], *bo=(const float*)d_in[24];
    const float* pos_u=(const float*)d_in[25], *pos_v=(const float*)d_in[26];
    const float* pw1_w=(const float*)d_in[27], *pw1_b=(const float*)d_in[28];
    const float* dw_w=(const float*)d_in[29],  *dw_b=(const float*)d_in[30];
    const float* bn_g=(const float*)d_in[31],  *bn_b=(const float*)d_in[32];
    const float* pw2_w=(const float*)d_in[33], *pw2_b=(const float*)d_in[34];
    const float* ff2_w1=(const float*)d_in[35], *ff2_b1=(const float*)d_in[36];
    const float* ff2_w2=(const float*)d_in[37], *ff2_b2=(const float*)d_in[38];

    char* W = (char*)d_ws;
    float* h     = (float*)(W + 0);            // 8MB f32
    u16*  xn     = (u16*) (W + (size_t)8*MB);  // 4MB
    u16*  wbuf   = (u16*) (W + (size_t)12*MB); // 4MB per-phase weights
    u16*  t1     = (u16*) (W + (size_t)16*MB); // 4MB
    u16*  qub    = (u16*) (W + (size_t)20*MB);
    u16*  qvb    = (u16*) (W + (size_t)24*MB);
    u16*  kb     = (u16*) (W + (size_t)28*MB);
    u16*  vt     = (u16*) (W + (size_t)32*MB); // (B,H,DK,T) bf16
    u16*  pproj  = (u16*) (W + (size_t)36*MB); // 2048x512 bf16
    u16*  posb   = (u16*) (W + (size_t)38*MB); // 2048x512 bf16
    char* big    = W + (size_t)40*MB;          // 64MB shared region
    u16*  ffh    = (u16*)big;                  // 16MB (FFN phases)
    u16*  acbuf  = (u16*)big;                  // 32MB (attn, becomes probs)
    u16*  bdsh   = (u16*)(big + (size_t)32*MB);// 32MB
    float* t2    = (float*)big;                // 16MB (conv)
    float* t3    = (float*)(big + (size_t)16*MB); // 8MB
    float* stats = (float*)(W + (size_t)104*MB);

    dim3 blk(256);
    const long S0 = 0;

    // ---------------- FFN1: h = x + 0.5*ffn(ln1(x)) ----------------
    transpose_bf16<<<dim3(64,16), blk, 0, stream>>>(ff1_w1, wbuf, 512, 2048);
    transpose_bf16<<<dim3(16,64), blk, 0, stream>>>(ff1_w2, wbuf + 1048576, 2048, 512);
    ln_kernel<1><<<dim3(NTOK), blk, 0, stream>>>(x, ln1_g, ln1_b, xn);
    bgemm<1><<<dim3(32,32,1), blk, 0, stream>>>(xn,512,S0,S0, wbuf,512,S0,S0,
        ffh,2048,S0,S0, 4096,2048,512, ff1_b1,1,1.f, nullptr,nullptr,nullptr,nullptr,0);
    bgemm<0><<<dim3(8,32,1), blk, 0, stream>>>(ffh,2048,S0,S0, wbuf+1048576,2048,S0,S0,
        h,512,S0,S0, 4096,512,2048, ff1_b2,0,0.5f, x,nullptr,nullptr,nullptr,0);

    // ---------------- Attention: h = h + attn(ln2(h)) ----------------
    transpose_bf16<<<dim3(16,16), blk, 0, stream>>>(wq, wbuf,          512, 512);
    transpose_bf16<<<dim3(16,16), blk, 0, stream>>>(wk, wbuf+262144,   512, 512);
    transpose_bf16<<<dim3(16,16), blk, 0, stream>>>(wv, wbuf+524288,   512, 512);
    transpose_bf16<<<dim3(16,16), blk, 0, stream>>>(wp, wbuf+786432,   512, 512);
    transpose_bf16<<<dim3(16,16), blk, 0, stream>>>(wo, wbuf+1048576,  512, 512);
    convert_pad<<<dim3(4096), blk, 0, stream>>>(pos_emb, posb, 2047*512, 2048*512);
    ln_kernel<1><<<dim3(NTOK), blk, 0, stream>>>(h, ln2_g, ln2_b, xn);
    bgemm<3><<<dim3(8,32,1), blk, 0, stream>>>(xn,512,S0,S0, wbuf,512,S0,S0,
        qub,512,S0,S0, 4096,512,512, bq,0,1.f, nullptr,pos_u,pos_v,qvb,0);
    bgemm<1><<<dim3(8,32,1), blk, 0, stream>>>(xn,512,S0,S0, wbuf+262144,512,S0,S0,
        kb,512,S0,S0, 4096,512,512, bk,0,1.f, nullptr,nullptr,nullptr,nullptr,0);
    bgemm<2><<<dim3(8,32,1), blk, 0, stream>>>(xn,512,S0,S0, wbuf+524288,512,S0,S0,
        vt,512,S0,S0, 4096,512,512, bv,0,1.f, nullptr,nullptr,nullptr,nullptr,0);
    bgemm<1><<<dim3(8,16,1), blk, 0, stream>>>(posb,512,S0,S0, wbuf+786432,512,S0,S0,
        pproj,512,S0,S0, 2048,512,512, nullptr,0,1.f, nullptr,nullptr,nullptr,nullptr,0);

    for (int g = 0; g < 2; ++g){
        const u16* qu_g = qub + (size_t)g*2*1024*512;
        const u16* qv_g = qvb + (size_t)g*2*1024*512;
        const u16* k_g  = kb  + (size_t)g*2*1024*512;
        const u16* v_g  = vt  + (size_t)g*2*8*64*1024;
        u16* t1_g = t1 + (size_t)g*2*1024*512;
        // ac = (q+u) @ K^T  -> acbuf (Z=16)
        bgemm<1><<<dim3(16,8,16), blk, 0, stream>>>(qu_g,512,524288,64, k_g,512,524288,64,
            acbuf,1024,8388608,1048576, 1024,1024,64, nullptr,0,1.f, nullptr,nullptr,nullptr,nullptr,0);
        // bd = (q+v) @ P^T, rel-shifted store -> bdsh (band-skipped)
        bgemm<4><<<dim3(32,8,16), blk, 0, stream>>>(qv_g,512,524288,64, pproj,512,0,64,
            bdsh,1024,8388608,1048576, 1024,2048,64, nullptr,0,1.f, nullptr,nullptr,nullptr,nullptr,1);
        shift_softmax_kernel<<<dim3(1024,16), blk, 0, stream>>>(acbuf, bdsh);
        // out = probs @ V  (B fragment from transposed V)
        bgemm<1><<<dim3(1,8,16), blk, 0, stream>>>(acbuf,1024,8388608,1048576, v_g,1024,524288,65536,
            t1_g,512,524288,64, 1024,64,1024, nullptr,0,1.f, nullptr,nullptr,nullptr,nullptr,0);
    }
    bgemm<0><<<dim3(8,32,1), blk, 0, stream>>>(t1,512,S0,S0, wbuf+1048576,512,S0,S0,
        h,512,S0,S0, 4096,512,512, bo,0,1.f, h,nullptr,nullptr,nullptr,0);

    // ---------------- Conv module ----------------
    convert_pad<<<dim3(2048), blk, 0, stream>>>(pw1_w, wbuf, 524288, 524288);
    convert_pad<<<dim3(1024), blk, 0, stream>>>(pw2_w, wbuf+524288, 262144, 262144);
    ln_kernel<1><<<dim3(NTOK), blk, 0, stream>>>(h, ln3_g, ln3_b, xn);
    bgemm<0><<<dim3(16,32,1), blk, 0, stream>>>(xn,512,S0,S0, wbuf,512,S0,S0,
        t2,1024,S0,S0, 4096,1024,512, pw1_b,0,1.f, nullptr,nullptr,nullptr,nullptr,0);
    glu_kernel<<<dim3(NTOK*DD/256), blk, 0, stream>>>(t2, t1);
    dwconv_kernel<<<dim3(NTOK*DD/256), blk, 0, stream>>>(t1, dw_w, dw_b, t3);
    bn_reduce_kernel<<<dim3(DD), blk, 0, stream>>>(t3, stats);
    bn_apply_kernel<<<dim3(NTOK*DD/256), blk, 0, stream>>>(t3, stats, bn_g, bn_b, t1);
    bgemm<0><<<dim3(8,32,1), blk, 0, stream>>>(t1,512,S0,S0, wbuf+524288,512,S0,S0,
        h,512,S0,S0, 4096,512,512, pw2_b,0,1.f, h,nullptr,nullptr,nullptr,0);

    // ---------------- FFN2 ----------------
    transpose_bf16<<<dim3(64,16), blk, 0, stream>>>(ff2_w1, wbuf, 512, 2048);
    transpose_bf16<<<dim3(16,64), blk, 0, stream>>>(ff2_w2, wbuf + 1048576, 2048, 512);
    ln_kernel<1><<<dim3(NTOK), blk, 0, stream>>>(h, ln4_g, ln4_b, xn);
    bgemm<1><<<dim3(32,32,1), blk, 0, stream>>>(xn,512,S0,S0, wbuf,512,S0,S0,
        ffh,2048,S0,S0, 4096,2048,512, ff2_b1,1,1.f, nullptr,nullptr,nullptr,nullptr,0);
    bgemm<0><<<dim3(8,32,1), blk, 0, stream>>>(ffh,2048,S0,S0, wbuf+1048576,2048,S0,S0,
        h,512,S0,S0, 4096,512,2048, ff2_b2,0,0.5f, h,nullptr,nullptr,nullptr,0);

    // ---------------- Final LN ----------------
    ln_kernel<0><<<dim3(NTOK), blk, 0, stream>>>(h, ln5_g, ln5_b, (float*)d_out);
}

// Round 3
// 485.926 us; speedup vs baseline: 6.3744x; 1.1212x over previous
//
#include <hip/hip_runtime.h>
#include <math.h>

#define TT   1024
#define BBZ  4
#define DD   512
#define DFF_ 2048
#define HH   8
#define DKK  64
#define NTOK 4096
#define EPSF 1e-5f
#define MB   1048576

typedef unsigned short u16;
typedef __attribute__((ext_vector_type(8))) short s8v;    // 8 bf16 (4 VGPRs)
typedef __attribute__((ext_vector_type(4))) float f32x4;

__device__ __forceinline__ float b2f(u16 v){
    union { unsigned int u; float f; } x; x.u = ((unsigned int)v) << 16; return x.f;
}
__device__ __forceinline__ u16 f2b(float f){
    union { float f; unsigned int u; } x; x.f = f;
    unsigned int r = x.u + 0x7fffu + ((x.u >> 16) & 1u);
    return (u16)(r >> 16);
}
__device__ __forceinline__ float sigmoidf_(float x){ return 1.0f/(1.0f+__expf(-x)); }

__device__ __forceinline__ void gld16(const u16* g, u16* l){
    __builtin_amdgcn_global_load_lds(
        (const __attribute__((address_space(1))) unsigned int*)g,
        (__attribute__((address_space(3))) unsigned int*)l, 16, 0, 0);
}

// ================= batched MFMA GEMM =================
// C = epilogue(A @ B^T_view), A:(M,K) bf16 row-major, B:(N,K) bf16 row-major.
// z-batched: zb=z>>3, zh=z&7; per-operand offsets off = zb*s_b + zh*s_h (elements).
// OMODE 0: f32 out (+bias, act, *alpha, +resid)   1: bf16 out (+bias, act)
// OMODE 2: bf16 V-transposed store                 3: bf16 dual (q+u),(q+v) store
// OMODE 4: bf16 rel-shifted ADD into C (band)
template<int OMODE>
__global__ __launch_bounds__(256) void bgemm(
    const u16* __restrict__ A, int lda, long sAb, long sAh,
    const u16* __restrict__ B, int ldb, long sBb, long sBh,
    void* __restrict__ Cv, int ldc, long sCb, long sCh,
    int M, int N, int K,
    const float* __restrict__ bias, int act, float alpha,
    const float* __restrict__ resid,
    const float* __restrict__ posu, const float* __restrict__ posv,
    u16* __restrict__ out2, int band)
{
    int z  = blockIdx.z;
    int zb = z >> 3, zh = z & 7;
    int n0 = blockIdx.x * 64;
    int m0 = blockIdx.y * 128;
    if (OMODE == 4 && band){
        // needed r range for rows [m0, m0+127]: [896-m0, 2046-m0]
        if (n0 + 63 < 896 - m0 || n0 > 2046 - m0) return;
    }
    const u16* Ab = A + (size_t)zb*sAb + (size_t)zh*sAh;
    const u16* Bb = B + (size_t)zb*sBb + (size_t)zh*sBh;

    __shared__ u16 As[128*64];
    __shared__ u16 Bs[64*64];

    int t = threadIdx.x;
    int w = t >> 6, l = t & 63;
    int lrow = l >> 3, lslot = l & 7;
    int kswz = (lslot ^ lrow) * 8;          // pre-swizzled global k-offset (elems)
    int wm = w >> 1, wn = w & 1;
    int lr = l & 15, lk = l >> 4;

    f32x4 acc[4][2] = {};

    for (int k0 = 0; k0 < K; k0 += 64){
        #pragma unroll
        for (int it = 0; it < 4; ++it){
            int rb = it*32 + w*8;
            gld16(Ab + (size_t)(m0 + rb + lrow)*lda + k0 + kswz, &As[rb*64]);
        }
        #pragma unroll
        for (int it = 0; it < 2; ++it){
            int rb = it*32 + w*8;
            gld16(Bb + (size_t)(n0 + rb + lrow)*ldb + k0 + kswz, &Bs[rb*64]);
        }
        __syncthreads();

        s8v af[2][4], bf[2][2];
        #pragma unroll
        for (int kh = 0; kh < 2; ++kh){
            #pragma unroll
            for (int mi = 0; mi < 4; ++mi){
                int row = wm*64 + mi*16 + lr;
                int sl  = (kh*4 + lk) ^ (lr & 7);
                af[kh][mi] = *(const s8v*)&As[row*64 + sl*8];
            }
            #pragma unroll
            for (int ni = 0; ni < 2; ++ni){
                int row = wn*32 + ni*16 + lr;
                int sl  = (kh*4 + lk) ^ (lr & 7);
                bf[kh][ni] = *(const s8v*)&Bs[row*64 + sl*8];
            }
        }
        #pragma unroll
        for (int kh = 0; kh < 2; ++kh)
            #pragma unroll
            for (int mi = 0; mi < 4; ++mi)
                #pragma unroll
                for (int ni = 0; ni < 2; ++ni)
                    acc[mi][ni] = __builtin_amdgcn_mfma_f32_16x16x32_bf16(
                        af[kh][mi], bf[kh][ni], acc[mi][ni], 0, 0, 0);
        __syncthreads();
    }

    // epilogue: col=lane&15, row=(lane>>4)*4+r
    #pragma unroll
    for (int mi = 0; mi < 4; ++mi){
        #pragma unroll
        for (int ni = 0; ni < 2; ++ni){
            int gn = n0 + wn*32 + ni*16 + lr;
            float bval = (OMODE == 4) ? 0.0f : (bias ? bias[gn] : 0.0f);
            #pragma unroll
            for (int r = 0; r < 4; ++r){
                int gm = m0 + wm*64 + mi*16 + lk*4 + r;
                float vv = acc[mi][ni][r] + bval;
                if (act) vv = vv * sigmoidf_(vv);
                if (OMODE == 0){
                    vv *= alpha;
                    if (resid) vv += resid[(size_t)gm*ldc + gn];
                    ((float*)Cv)[(size_t)zb*sCb + (size_t)zh*sCh + (size_t)gm*ldc + gn] = vv;
                } else if (OMODE == 1){
                    ((u16*)Cv)[(size_t)zb*sCb + (size_t)zh*sCh + (size_t)gm*ldc + gn] = f2b(vv);
                } else if (OMODE == 2){
                    int bb = gm >> 10, tt2 = gm & 1023;
                    size_t idx = (((size_t)(bb*8 + (gn>>6)))*64 + (gn&63))*1024 + tt2;
                    ((u16*)Cv)[idx] = f2b(vv);
                } else if (OMODE == 3){
                    size_t idx = (size_t)gm*ldc + gn;
                    ((u16*)Cv)[idx] = f2b(vv + posu[gn]);
                    out2[idx]       = f2b(vv + posv[gn]);
                } else { // 4: rel-shifted ADD into existing ac scores
                    int j = gn - 1023 + gm;
                    if (j >= 0 && j < 1024){
                        u16* pC = (u16*)Cv + (size_t)zb*sCb + (size_t)zh*sCh + (size_t)gm*1024 + j;
                        *pC = f2b(b2f(*pC) + vv);
                    }
                }
            }
        }
    }
}

// ================= LayerNorm (f32 in, bf16/f32 out) =================
template<int OB>
__global__ __launch_bounds__(256) void ln_kernel(const float* __restrict__ in,
    const float* __restrict__ g, const float* __restrict__ b, void* __restrict__ outv)
{
    int row = blockIdx.x, t = threadIdx.x;
    const float* x = in + (size_t)row*DD;
    float v0 = x[t], v1 = x[t+256];
    __shared__ float rs[256], rq[256];
    rs[t] = v0+v1; rq[t] = v0*v0+v1*v1;
    __syncthreads();
    for (int st=128; st>0; st>>=1){
        if (t<st){ rs[t]+=rs[t+st]; rq[t]+=rq[t+st]; }
        __syncthreads();
    }
    float mean = rs[0]*(1.0f/DD);
    float var  = rq[0]*(1.0f/DD) - mean*mean;
    float inv  = rsqrtf(var+EPSF);
    float y0 = (v0-mean)*inv*g[t]     + b[t];
    float y1 = (v1-mean)*inv*g[t+256] + b[t+256];
    if (OB){
        u16* o = (u16*)outv;
        o[(size_t)row*DD+t] = f2b(y0); o[(size_t)row*DD+t+256] = f2b(y1);
    } else {
        float* o = (float*)outv;
        o[(size_t)row*DD+t] = y0; o[(size_t)row*DD+t+256] = y1;
    }
}

// ================= consolidated weight prep =================
struct Prep9 {
    const float* s[9];
    u16* d[9];
    int R[9], C[9];
    int t0[10];
};

__global__ __launch_bounds__(256) void prep_transpose(Prep9 P)
{
    __shared__ float tile[32][33];
    int bid = blockIdx.x;
    int j = 0;
    #pragma unroll
    for (int e=1; e<9; e++) if (bid >= P.t0[e]) j = e;
    int lb = bid - P.t0[j];
    int nx = P.C[j] >> 5;
    int c0 = (lb % nx) << 5;
    int r0 = (lb / nx) << 5;
    const float* in = P.s[j];
    u16* out = P.d[j];
    int R = P.R[j], C = P.C[j];
    int tx = threadIdx.x & 31, ty = threadIdx.x >> 5;
    #pragma unroll
    for (int i=0;i<4;i++){
        int rr = ty + i*8;
        tile[rr][tx] = in[(size_t)(r0+rr)*C + c0+tx];
    }
    __syncthreads();
    #pragma unroll
    for (int i=0;i<4;i++){
        int cc = ty + i*8;
        out[(size_t)(c0+cc)*R + r0+tx] = f2b(tile[tx][cc]);
    }
}

__global__ __launch_bounds__(256) void prep_convert(
    const float* __restrict__ pw1_w, const float* __restrict__ pw2_w,
    const float* __restrict__ pos_emb, const float* __restrict__ dw_w,
    u16* __restrict__ pw1b, u16* __restrict__ pw2b,
    u16* __restrict__ posb, float* __restrict__ wt)
{
    int i = blockIdx.x*256 + threadIdx.x;
    if (i < 524288) { pw1b[i] = f2b(pw1_w[i]); return; }
    i -= 524288;
    if (i < 262144) { pw2b[i] = f2b(pw2_w[i]); return; }
    i -= 262144;
    if (i < 1048576) { posb[i] = (i < 2047*512) ? f2b(pos_emb[i]) : (u16)0; return; }
    i -= 1048576;
    if (i < 15872) { int kk = i >> 9, d = i & 511; wt[i] = dw_w[d*31+kk]; }
}

// ================= softmax over rows of raw scores *0.125, in-place bf16 =================
__global__ __launch_bounds__(256) void row_softmax(u16* __restrict__ sc)
{
    size_t base = ((size_t)blockIdx.y*1024 + blockIdx.x)*1024;
    int t = threadIdx.x;
    float s[4]; float mx = -1e30f;
    #pragma unroll
    for (int e=0;e<4;e++){
        s[e] = b2f(sc[base + t + 256*e])*0.125f;
        mx = fmaxf(mx, s[e]);
    }
    __shared__ float red[256];
    red[t]=mx; __syncthreads();
    for (int st=128; st>0; st>>=1){ if(t<st) red[t]=fmaxf(red[t],red[t+st]); __syncthreads(); }
    mx = red[0]; __syncthreads();
    float sum = 0.f;
    #pragma unroll
    for (int e=0;e<4;e++){ s[e]=__expf(s[e]-mx); sum+=s[e]; }
    red[t]=sum; __syncthreads();
    for (int st=128; st>0; st>>=1){ if(t<st) red[t]+=red[t+st]; __syncthreads(); }
    float inv = 1.0f/red[0];
    #pragma unroll
    for (int e=0;e<4;e++) sc[base + t + 256*e] = f2b(s[e]*inv);
}

// ================= conv-module elementwise =================
__global__ __launch_bounds__(256) void glu_kernel(const float* __restrict__ in, u16* __restrict__ out)
{
    int idx = blockIdx.x*256 + threadIdx.x;
    int r = idx >> 9, c = idx & 511;
    float a  = in[(size_t)r*1024 + c];
    float gg = in[(size_t)r*1024 + 512 + c];
    out[idx] = f2b(a * sigmoidf_(gg));
}

// depthwise conv K=31: each thread = one d, 8 consecutive t (register sliding window)
__global__ __launch_bounds__(256) void dwconv_kernel(const u16* __restrict__ y,
    const float* __restrict__ wt, const float* __restrict__ bias, float* __restrict__ z)
{
    int d  = blockIdx.x*256 + threadIdx.x;   // gridDim.x = 2
    int c  = blockIdx.y;                     // 0..511
    int b  = c >> 7;
    int t0 = (c & 127) << 3;
    const u16* yb = y + (size_t)b*TT*DD + d;
    float wv[31];
    #pragma unroll
    for (int kk=0;kk<31;kk++) wv[kk] = wt[kk*512 + d];   // coalesced (pre-transposed)
    float xv[38];
    #pragma unroll
    for (int e=0;e<38;e++){
        int tp = t0 - 15 + e;
        xv[e] = (tp>=0 && tp<TT) ? b2f(yb[(size_t)tp*DD]) : 0.0f;
    }
    float bsv = bias[d];
    #pragma unroll
    for (int j=0;j<8;j++){
        float s = bsv;
        #pragma unroll
        for (int kk=0;kk<31;kk++) s = fmaf(xv[j+kk], wv[kk], s);
        z[(size_t)(b*TT+t0+j)*DD + d] = s;
    }
}

__global__ __launch_bounds__(256) void bn_reduce_kernel(const float* __restrict__ z, float* __restrict__ stats)
{
    int c = blockIdx.x, t = threadIdx.x;
    float s=0.f, q=0.f;
    for (int r=t; r<NTOK; r+=256){
        float vv = z[(size_t)r*DD + c];
        s += vv; q += vv*vv;
    }
    __shared__ float rs[256], rq[256];
    rs[t]=s; rq[t]=q; __syncthreads();
    for (int st=128; st>0; st>>=1){
        if (t<st){ rs[t]+=rs[t+st]; rq[t]+=rq[t+st]; }
        __syncthreads();
    }
    if (t==0){ stats[c]=rs[0]; stats[DD+c]=rq[0]; }
}

__global__ __launch_bounds__(256) void bn_apply_kernel(const float* __restrict__ z,
    const float* __restrict__ stats, const float* __restrict__ g, const float* __restrict__ b,
    u16* __restrict__ out)
{
    int idx = blockIdx.x*256 + threadIdx.x;
    int c = idx & (DD-1);
    float m   = stats[c]*(1.0f/NTOK);
    float var = stats[DD+c]*(1.0f/NTOK) - m*m;
    float vv  = (z[idx]-m)*rsqrtf(var+EPSF)*g[c] + b[c];
    out[idx]  = f2b(vv*sigmoidf_(vv));
}

extern "C" void kernel_launch(void* const* d_in, const int* in_sizes, int n_in,
                              void* d_out, int out_size, void* d_ws, size_t ws_size,
                              hipStream_t stream)
{
    const float* x       = (const float*)d_in[0];
    const float* pos_emb = (const float*)d_in[1];
    const float* ln1_g=(const float*)d_in[2],  *ln1_b=(const float*)d_in[3];
    const float* ln2_g=(const float*)d_in[4],  *ln2_b=(const float*)d_in[5];
    const float* ln3_g=(const float*)d_in[6],  *ln3_b=(const float*)d_in[7];
    const float* ln4_g=(const float*)d_in[8],  *ln4_b=(const float*)d_in[9];
    const float* ln5_g=(const float*)d_in[10], *ln5_b=(const float*)d_in[11];
    const float* ff1_w1=(const float*)d_in[12], *ff1_b1=(const float*)d_in[13];
    const float* ff1_w2=(const float*)d_in[14], *ff1_b2=(const float*)d_in[15];
    const float* wq=(const float*)d_in[16], *bq=(const float*)d_in[17];
    const float* wk=(const float*)d_in[18], *bk=(const float*)d_in[19];
    const float* wv=(const float*)d_in[20], *bv=(const float*)d_in[21];
    const float* wp=(const float*)d_in[22];
    const float* wo=(const float*)d_in[23], *bo=(const float*)d_in[24];
    const float* pos_u=(const float*)d_in[25], *pos_v=(const float*)d_in[26];
    const float* pw1_w=(const float*)d_in[27], *pw1_b=(const float*)d_in[28];
    const float* dw_w=(const float*)d_in[29],  *dw_b=(const float*)d_in[30];
    const float* bn_g=(const float*)d_in[31],  *bn_b=(const float*)d_in[32];
    const float* pw2_w=(const float*)d_in[33], *pw2_b=(const float*)d_in[34];
    const float* ff2_w1=(const float*)d_in[35], *ff2_b1=(const float*)d_in[36];
    const float* ff2_w2=(const float*)d_in[37], *ff2_b2=(const float*)d_in[38];

    char* W = (char*)d_ws;
    float* h    = (float*)(W);                  // 8 MB f32
    u16*  xn    = (u16*) (W + (size_t) 8*MB);   // 4 MB (ln out / attn out / glu out)
    u16*  wall  = (u16*) (W + (size_t)12*MB);   // 16 MB all prepped weights
    u16*  qub   = (u16*) (W + (size_t)28*MB);
    u16*  qvb   = (u16*) (W + (size_t)32*MB);
    u16*  kb    = (u16*) (W + (size_t)36*MB);
    u16*  vt    = (u16*) (W + (size_t)40*MB);   // (B,H,DK,T)
    u16*  pproj = (u16*) (W + (size_t)44*MB);   // 2048x512
    char* big   = W + (size_t)48*MB;            // 64 MB
    u16*  acbuf = (u16*)big;                    // 64 MB scores (z=32)
    u16*  ffh   = (u16*)big;                    // 16 MB FFN hidden
    float* t2   = (float*)big;                  // 16 MB conv pw1 out
    float* t3   = (float*)(big + (size_t)16*MB);// 8 MB dwconv out
    float* stats= (float*)(W + (size_t)112*MB); // 4 KB
    float* wt   = stats + 4096;                 // 63.5 KB (31,512) f32

    u16* ff1w1T = wall;
    u16* ff1w2T = wall + 1048576;
    u16* wqT    = wall + 2097152;
    u16* wkT    = wall + 2359296;
    u16* wvT    = wall + 2621440;
    u16* wpT    = wall + 2883584;
    u16* woT    = wall + 3145728;
    u16* ff2w1T = wall + 3407872;
    u16* ff2w2T = wall + 4456448;
    u16* pw1b   = wall + 5505024;
    u16* pw2b   = wall + 6029312;
    u16* posb   = wall + 6291456;

    dim3 blk(256);
    const long S0 = 0;

    // ---------------- weight prep (2 launches) ----------------
    Prep9 P;
    P.s[0]=ff1_w1; P.d[0]=ff1w1T; P.R[0]=512;  P.C[0]=2048;
    P.s[1]=ff1_w2; P.d[1]=ff1w2T; P.R[1]=2048; P.C[1]=512;
    P.s[2]=wq;     P.d[2]=wqT;    P.R[2]=512;  P.C[2]=512;
    P.s[3]=wk;     P.d[3]=wkT;    P.R[3]=512;  P.C[3]=512;
    P.s[4]=wv;     P.d[4]=wvT;    P.R[4]=512;  P.C[4]=512;
    P.s[5]=wp;     P.d[5]=wpT;    P.R[5]=512;  P.C[5]=512;
    P.s[6]=wo;     P.d[6]=woT;    P.R[6]=512;  P.C[6]=512;
    P.s[7]=ff2_w1; P.d[7]=ff2w1T; P.R[7]=512;  P.C[7]=2048;
    P.s[8]=ff2_w2; P.d[8]=ff2w2T; P.R[8]=2048; P.C[8]=512;
    int tc[9] = {1024,1024,256,256,256,256,256,1024,1024};
    P.t0[0]=0; for (int e=0;e<9;e++) P.t0[e+1]=P.t0[e]+tc[e];
    prep_transpose<<<dim3(5376), blk, 0, stream>>>(P);
    prep_convert<<<dim3(7230), blk, 0, stream>>>(pw1_w, pw2_w, pos_emb, dw_w,
                                                 pw1b, pw2b, posb, wt);

    // ---------------- FFN1: h = x + 0.5*ffn(ln1(x)) ----------------
    ln_kernel<1><<<dim3(NTOK), blk, 0, stream>>>(x, ln1_g, ln1_b, xn);
    bgemm<1><<<dim3(32,32,1), blk, 0, stream>>>(xn,512,S0,S0, ff1w1T,512,S0,S0,
        ffh,2048,S0,S0, 4096,2048,512, ff1_b1,1,1.f, nullptr,nullptr,nullptr,nullptr,0);
    bgemm<0><<<dim3(8,32,1), blk, 0, stream>>>(ffh,2048,S0,S0, ff1w2T,2048,S0,S0,
        h,512,S0,S0, 4096,512,2048, ff1_b2,0,0.5f, x,nullptr,nullptr,nullptr,0);

    // ---------------- Attention: h = h + attn(ln2(h)) ----------------
    ln_kernel<1><<<dim3(NTOK), blk, 0, stream>>>(h, ln2_g, ln2_b, xn);
    bgemm<3><<<dim3(8,32,1), blk, 0, stream>>>(xn,512,S0,S0, wqT,512,S0,S0,
        qub,512,S0,S0, 4096,512,512, bq,0,1.f, nullptr,pos_u,pos_v,qvb,0);
    bgemm<1><<<dim3(8,32,1), blk, 0, stream>>>(xn,512,S0,S0, wkT,512,S0,S0,
        kb,512,S0,S0, 4096,512,512, bk,0,1.f, nullptr,nullptr,nullptr,nullptr,0);
    bgemm<2><<<dim3(8,32,1), blk, 0, stream>>>(xn,512,S0,S0, wvT,512,S0,S0,
        vt,512,S0,S0, 4096,512,512, bv,0,1.f, nullptr,nullptr,nullptr,nullptr,0);
    bgemm<1><<<dim3(8,16,1), blk, 0, stream>>>(posb,512,S0,S0, wpT,512,S0,S0,
        pproj,512,S0,S0, 2048,512,512, nullptr,0,1.f, nullptr,nullptr,nullptr,nullptr,0);

    // scores: ac = (q+u)K^T   (all 32 (b,h) at once)
    bgemm<1><<<dim3(16,8,32), blk, 0, stream>>>(qub,512,524288,64, kb,512,524288,64,
        acbuf,1024,8388608,1048576, 1024,1024,64, nullptr,0,1.f, nullptr,nullptr,nullptr,nullptr,0);
    // bd = (q+v)P^T, rel-shifted ADD into acbuf (band-skipped)
    bgemm<4><<<dim3(32,8,32), blk, 0, stream>>>(qvb,512,524288,64, pproj,512,0,64,
        acbuf,1024,8388608,1048576, 1024,2048,64, nullptr,0,1.f, nullptr,nullptr,nullptr,nullptr,1);
    row_softmax<<<dim3(1024,32), blk, 0, stream>>>(acbuf);
    // out = probs @ V  -> xn   (256 blocks = full GPU)
    bgemm<1><<<dim3(1,8,32), blk, 0, stream>>>(acbuf,1024,8388608,1048576, vt,1024,524288,65536,
        xn,512,524288,64, 1024,64,1024, nullptr,0,1.f, nullptr,nullptr,nullptr,nullptr,0);
    bgemm<0><<<dim3(8,32,1), blk, 0, stream>>>(xn,512,S0,S0, woT,512,S0,S0,
        h,512,S0,S0, 4096,512,512, bo,0,1.f, h,nullptr,nullptr,nullptr,0);

    // ---------------- Conv module ----------------
    ln_kernel<1><<<dim3(NTOK), blk, 0, stream>>>(h, ln3_g, ln3_b, xn);
    bgemm<0><<<dim3(16,32,1), blk, 0, stream>>>(xn,512,S0,S0, pw1b,512,S0,S0,
        t2,1024,S0,S0, 4096,1024,512, pw1_b,0,1.f, nullptr,nullptr,nullptr,nullptr,0);
    glu_kernel<<<dim3(NTOK*DD/256), blk, 0, stream>>>(t2, xn);
    dwconv_kernel<<<dim3(2,512), blk, 0, stream>>>(xn, wt, dw_b, t3);
    bn_reduce_kernel<<<dim3(DD), blk, 0, stream>>>(t3, stats);
    bn_apply_kernel<<<dim3(NTOK*DD/256), blk, 0, stream>>>(t3, stats, bn_g, bn_b, xn);
    bgemm<0><<<dim3(8,32,1), blk, 0, stream>>>(xn,512,S0,S0, pw2b,512,S0,S0,
        h,512,S0,S0, 4096,512,512, pw2_b,0,1.f, h,nullptr,nullptr,nullptr,0);

    // ---------------- FFN2 ----------------
    ln_kernel<1><<<dim3(NTOK), blk, 0, stream>>>(h, ln4_g, ln4_b, xn);
    bgemm<1><<<dim3(32,32,1), blk, 0, stream>>>(xn,512,S0,S0, ff2w1T,512,S0,S0,
        ffh,2048,S0,S0, 4096,2048,512, ff2_b1,1,1.f, nullptr,nullptr,nullptr,nullptr,0);
    bgemm<0><<<dim3(8,32,1), blk, 0, stream>>>(ffh,2048,S0,S0, ff2w2T,2048,S0,S0,
        h,512,S0,S0, 4096,512,2048, ff2_b2,0,0.5f, h,nullptr,nullptr,nullptr,0);

    // ---------------- Final LN ----------------
    ln_kernel<0><<<dim3(NTOK), blk, 0, stream>>>(h, ln5_g, ln5_b, (float*)d_out);
}

// Round 4
// 373.418 us; speedup vs baseline: 8.2950x; 1.3013x over previous
//
#include <hip/hip_runtime.h>
#include <math.h>

#define TT   1024
#define BBZ  4
#define DD   512
#define DFF_ 2048
#define HH   8
#define DKK  64
#define NTOK 4096
#define EPSF 1e-5f
#define MB   1048576

typedef unsigned short u16;
typedef __attribute__((ext_vector_type(8))) short s8v;    // 8 bf16 (4 VGPRs)
typedef __attribute__((ext_vector_type(4))) float f32x4;

__device__ __forceinline__ float b2f(u16 v){
    union { unsigned int u; float f; } x; x.u = ((unsigned int)v) << 16; return x.f;
}
__device__ __forceinline__ u16 f2b(float f){
    union { float f; unsigned int u; } x; x.f = f;
    unsigned int r = x.u + 0x7fffu + ((x.u >> 16) & 1u);
    return (u16)(r >> 16);
}
__device__ __forceinline__ float sigmoidf_(float x){ return 1.0f/(1.0f+__expf(-x)); }

__device__ __forceinline__ void gld16(const u16* g, u16* l){
    __builtin_amdgcn_global_load_lds(
        (const __attribute__((address_space(1))) unsigned int*)g,
        (__attribute__((address_space(3))) unsigned int*)l, 16, 0, 0);
}

// ================= batched MFMA GEMM =================
// C = epilogue(A @ B^T_view), A:(M,K) bf16 row-major, B:(N,K) bf16 row-major.
// OMODE 0: f32 out (+bias, act, *alpha, +resid)   1: bf16 out (+bias, act)
// OMODE 2: bf16 V-transposed store                 3: bf16 dual (q+u),(q+v) store
template<int OMODE>
__global__ __launch_bounds__(256) void bgemm(
    const u16* __restrict__ A, int lda, long sAb, long sAh,
    const u16* __restrict__ B, int ldb, long sBb, long sBh,
    void* __restrict__ Cv, int ldc, long sCb, long sCh,
    int M, int N, int K,
    const float* __restrict__ bias, int act, float alpha,
    const float* __restrict__ resid,
    const float* __restrict__ posu, const float* __restrict__ posv,
    u16* __restrict__ out2)
{
    int z  = blockIdx.z;
    int zb = z >> 3, zh = z & 7;
    int n0 = blockIdx.x * 64;
    int m0 = blockIdx.y * 128;
    const u16* Ab = A + (size_t)zb*sAb + (size_t)zh*sAh;
    const u16* Bb = B + (size_t)zb*sBb + (size_t)zh*sBh;

    __shared__ u16 As[128*64];
    __shared__ u16 Bs[64*64];

    int t = threadIdx.x;
    int w = t >> 6, l = t & 63;
    int lrow = l >> 3, lslot = l & 7;
    int kswz = (lslot ^ lrow) * 8;
    int wm = w >> 1, wn = w & 1;
    int lr = l & 15, lk = l >> 4;

    f32x4 acc[4][2] = {};

    for (int k0 = 0; k0 < K; k0 += 64){
        #pragma unroll
        for (int it = 0; it < 4; ++it){
            int rb = it*32 + w*8;
            gld16(Ab + (size_t)(m0 + rb + lrow)*lda + k0 + kswz, &As[rb*64]);
        }
        #pragma unroll
        for (int it = 0; it < 2; ++it){
            int rb = it*32 + w*8;
            gld16(Bb + (size_t)(n0 + rb + lrow)*ldb + k0 + kswz, &Bs[rb*64]);
        }
        __syncthreads();

        s8v af[2][4], bf[2][2];
        #pragma unroll
        for (int kh = 0; kh < 2; ++kh){
            #pragma unroll
            for (int mi = 0; mi < 4; ++mi){
                int row = wm*64 + mi*16 + lr;
                int sl  = (kh*4 + lk) ^ (lr & 7);
                af[kh][mi] = *(const s8v*)&As[row*64 + sl*8];
            }
            #pragma unroll
            for (int ni = 0; ni < 2; ++ni){
                int row = wn*32 + ni*16 + lr;
                int sl  = (kh*4 + lk) ^ (lr & 7);
                bf[kh][ni] = *(const s8v*)&Bs[row*64 + sl*8];
            }
        }
        #pragma unroll
        for (int kh = 0; kh < 2; ++kh)
            #pragma unroll
            for (int mi = 0; mi < 4; ++mi)
                #pragma unroll
                for (int ni = 0; ni < 2; ++ni)
                    acc[mi][ni] = __builtin_amdgcn_mfma_f32_16x16x32_bf16(
                        af[kh][mi], bf[kh][ni], acc[mi][ni], 0, 0, 0);
        __syncthreads();
    }

    #pragma unroll
    for (int mi = 0; mi < 4; ++mi){
        #pragma unroll
        for (int ni = 0; ni < 2; ++ni){
            int gn = n0 + wn*32 + ni*16 + lr;
            float bval = bias ? bias[gn] : 0.0f;
            #pragma unroll
            for (int r = 0; r < 4; ++r){
                int gm = m0 + wm*64 + mi*16 + lk*4 + r;
                float vv = acc[mi][ni][r] + bval;
                if (act) vv = vv * sigmoidf_(vv);
                if (OMODE == 0){
                    vv *= alpha;
                    if (resid) vv += resid[(size_t)gm*ldc + gn];
                    ((float*)Cv)[(size_t)zb*sCb + (size_t)zh*sCh + (size_t)gm*ldc + gn] = vv;
                } else if (OMODE == 1){
                    ((u16*)Cv)[(size_t)zb*sCb + (size_t)zh*sCh + (size_t)gm*ldc + gn] = f2b(vv);
                } else if (OMODE == 2){
                    int bb = gm >> 10, tt2 = gm & 1023;
                    size_t idx = (((size_t)(bb*8 + (gn>>6)))*64 + (gn&63))*1024 + tt2;
                    ((u16*)Cv)[idx] = f2b(vv);
                } else { // 3
                    size_t idx = (size_t)gm*ldc + gn;
                    ((u16*)Cv)[idx] = f2b(vv + posu[gn]);
                    out2[idx]       = f2b(vv + posv[gn]);
                }
            }
        }
    }
}

// ================= fused rel-pos flash attention =================
// grid (T/64, 32);  z = b*8+h.  Computes softmax((qu K^T + shift(qv P^T))*0.125) V
__global__ __launch_bounds__(256) void attn_fused(
    const u16* __restrict__ qub, const u16* __restrict__ qvb,
    const u16* __restrict__ kb,  const u16* __restrict__ vt,
    const u16* __restrict__ pp,  u16* __restrict__ out)
{
    int z = blockIdx.y;
    int b = z >> 3, hh = z & 7;
    int i0 = blockIdx.x * 64;

    __shared__ u16 Ks[64*64];
    __shared__ u16 VT[64*64];
    __shared__ u16 Ps[128*64];
    __shared__ u16 Gb[64*136];   // G band buffer (stride 136); aliased as swizzled P-tilde

    int t = threadIdx.x;
    int w = t >> 6, l = t & 63;
    int lrow = l >> 3, lslot = l & 7;
    int kswz = (lslot ^ lrow) * 8;
    int lr = l & 15, lk = l >> 4;

    // ---- stage Q tiles (qu -> Ps rows 0..63, qv -> rows 64..127), frags to regs ----
    #pragma unroll
    for (int it = 0; it < 2; ++it){
        int rb = it*32 + w*8;
        gld16(qub + (size_t)(b*TT + i0 + rb + lrow)*DD + hh*64 + kswz, &Ps[rb*64]);
        gld16(qvb + (size_t)(b*TT + i0 + rb + lrow)*DD + hh*64 + kswz, &Ps[(64+rb)*64]);
    }
    __syncthreads();
    s8v af_u[2], af_v[2];
    #pragma unroll
    for (int kh = 0; kh < 2; ++kh){
        int sl = (kh*4 + lk) ^ (lr & 7);
        af_u[kh] = *(const s8v*)&Ps[(w*16 + lr)*64 + sl*8];
        af_v[kh] = *(const s8v*)&Ps[(64 + w*16 + lr)*64 + sl*8];
    }

    f32x4 o[4] = {};
    float M_[4], L_[4];
    #pragma unroll
    for (int r = 0; r < 4; ++r){ M_[r] = -1e30f; L_[r] = 0.0f; }

    for (int j0 = 0; j0 < TT; j0 += 64){
        __syncthreads();   // staged buffers free (prev PV / initial frag reads done)
        int r0 = 960 + j0 - i0;
        #pragma unroll
        for (int it = 0; it < 2; ++it){
            int rb = it*32 + w*8;
            gld16(kb + (size_t)(b*TT + j0 + rb + lrow)*DD + hh*64 + kswz, &Ks[rb*64]);
            gld16(vt + ((size_t)z*64 + rb + lrow)*TT + j0 + kswz, &VT[rb*64]);
        }
        #pragma unroll
        for (int it = 0; it < 4; ++it){
            int rb = it*32 + w*8;
            gld16(pp + (size_t)(r0 + rb + lrow)*DD + hh*64 + kswz, &Ps[rb*64]);
        }
        __syncthreads();

        // ---- S_ac (16x64) and G (16x128) per wave ----
        f32x4 sac[4] = {};
        f32x4 g[8] = {};
        #pragma unroll
        for (int kh = 0; kh < 2; ++kh){
            int sl = (kh*4 + lk) ^ (lr & 7);
            #pragma unroll
            for (int n = 0; n < 4; ++n){
                s8v bK = *(const s8v*)&Ks[(n*16 + lr)*64 + sl*8];
                sac[n] = __builtin_amdgcn_mfma_f32_16x16x32_bf16(af_u[kh], bK, sac[n], 0,0,0);
            }
            #pragma unroll
            for (int n = 0; n < 8; ++n){
                s8v bP = *(const s8v*)&Ps[(n*16 + lr)*64 + sl*8];
                g[n] = __builtin_amdgcn_mfma_f32_16x16x32_bf16(af_v[kh], bP, g[n], 0,0,0);
            }
        }
        // write G to LDS (C layout)
        #pragma unroll
        for (int n = 0; n < 8; ++n)
            #pragma unroll
            for (int r = 0; r < 4; ++r){
                int ii = w*16 + (l>>4)*4 + r;
                Gb[ii*136 + n*16 + (l&15)] = f2b(g[n][r]);
            }
        __syncthreads();

        // ---- combine band + online softmax ----
        float p_[4][4], sc_[4];
        #pragma unroll
        for (int r = 0; r < 4; ++r){
            int ii = w*16 + (l>>4)*4 + r;
            float sv[4]; float mx = -1e30f;
            #pragma unroll
            for (int n = 0; n < 4; ++n){
                int jj = n*16 + (l&15);
                float vvv = (sac[n][r] + b2f(Gb[ii*136 + 63 + jj - ii])) * 0.125f;
                sv[n] = vvv; mx = fmaxf(mx, vvv);
            }
            #pragma unroll
            for (int msk = 1; msk < 16; msk <<= 1) mx = fmaxf(mx, __shfl_xor(mx, msk));
            float nm = fmaxf(M_[r], mx);
            float scale = __expf(M_[r] - nm);
            float rs = 0.0f;
            #pragma unroll
            for (int n = 0; n < 4; ++n){ p_[n][r] = __expf(sv[n] - nm); rs += p_[n][r]; }
            #pragma unroll
            for (int msk = 1; msk < 16; msk <<= 1) rs += __shfl_xor(rs, msk);
            L_[r] = L_[r]*scale + rs;
            M_[r] = nm;
            sc_[r] = scale;
        }
        #pragma unroll
        for (int n = 0; n < 4; ++n)
            #pragma unroll
            for (int r = 0; r < 4; ++r)
                o[n][r] *= sc_[r];
        __syncthreads();   // all G reads done before P-tilde overwrites Gb

        // write P-tilde (swizzled) into Gb
        #pragma unroll
        for (int n = 0; n < 4; ++n)
            #pragma unroll
            for (int r = 0; r < 4; ++r){
                int ii  = w*16 + (l>>4)*4 + r;
                int col = n*16 + (l&15);
                int sl  = (col>>3) ^ (ii&7);
                Gb[ii*64 + sl*8 + (col&7)] = f2b(p_[n][r]);
            }
        __syncthreads();

        // ---- PV ----
        #pragma unroll
        for (int kh = 0; kh < 2; ++kh){
            int sl = (kh*4 + lk) ^ (lr & 7);
            s8v ap = *(const s8v*)&Gb[(w*16 + lr)*64 + sl*8];
            #pragma unroll
            for (int n = 0; n < 4; ++n){
                s8v bV = *(const s8v*)&VT[(n*16 + lr)*64 + sl*8];
                o[n] = __builtin_amdgcn_mfma_f32_16x16x32_bf16(ap, bV, o[n], 0,0,0);
            }
        }
    }

    #pragma unroll
    for (int n = 0; n < 4; ++n)
        #pragma unroll
        for (int r = 0; r < 4; ++r){
            int i  = i0 + w*16 + (l>>4)*4 + r;
            int dk = n*16 + (l&15);
            out[(size_t)(b*TT + i)*DD + hh*64 + dk] = f2b(o[n][r] / L_[r]);
        }
}

// ================= LayerNorm (f32 in, bf16/f32 out) =================
template<int OB>
__global__ __launch_bounds__(256) void ln_kernel(const float* __restrict__ in,
    const float* __restrict__ g, const float* __restrict__ b, void* __restrict__ outv)
{
    int row = blockIdx.x, t = threadIdx.x;
    const float* x = in + (size_t)row*DD;
    float v0 = x[t], v1 = x[t+256];
    __shared__ float rs[256], rq[256];
    rs[t] = v0+v1; rq[t] = v0*v0+v1*v1;
    __syncthreads();
    for (int st=128; st>0; st>>=1){
        if (t<st){ rs[t]+=rs[t+st]; rq[t]+=rq[t+st]; }
        __syncthreads();
    }
    float mean = rs[0]*(1.0f/DD);
    float var  = rq[0]*(1.0f/DD) - mean*mean;
    float inv  = rsqrtf(var+EPSF);
    float y0 = (v0-mean)*inv*g[t]     + b[t];
    float y1 = (v1-mean)*inv*g[t+256] + b[t+256];
    if (OB){
        u16* o = (u16*)outv;
        o[(size_t)row*DD+t] = f2b(y0); o[(size_t)row*DD+t+256] = f2b(y1);
    } else {
        float* o = (float*)outv;
        o[(size_t)row*DD+t] = y0; o[(size_t)row*DD+t+256] = y1;
    }
}

// ================= consolidated weight prep =================
struct Prep9 {
    const float* s[9];
    u16* d[9];
    int R[9], C[9];
    int t0[10];
};

__global__ __launch_bounds__(256) void prep_transpose(Prep9 P)
{
    __shared__ float tile[32][33];
    int bid = blockIdx.x;
    int j = 0;
    #pragma unroll
    for (int e=1; e<9; e++) if (bid >= P.t0[e]) j = e;
    int lb = bid - P.t0[j];
    int nx = P.C[j] >> 5;
    int c0 = (lb % nx) << 5;
    int r0 = (lb / nx) << 5;
    const float* in = P.s[j];
    u16* out = P.d[j];
    int R = P.R[j], C = P.C[j];
    int tx = threadIdx.x & 31, ty = threadIdx.x >> 5;
    #pragma unroll
    for (int i=0;i<4;i++){
        int rr = ty + i*8;
        tile[rr][tx] = in[(size_t)(r0+rr)*C + c0+tx];
    }
    __syncthreads();
    #pragma unroll
    for (int i=0;i<4;i++){
        int cc = ty + i*8;
        out[(size_t)(c0+cc)*R + r0+tx] = f2b(tile[tx][cc]);
    }
}

__global__ __launch_bounds__(256) void prep_convert(
    const float* __restrict__ pw1_w, const float* __restrict__ pw2_w,
    const float* __restrict__ pos_emb, const float* __restrict__ dw_w,
    u16* __restrict__ pw1b, u16* __restrict__ pw2b,
    u16* __restrict__ posb, float* __restrict__ wt)
{
    int i = blockIdx.x*256 + threadIdx.x;
    if (i < 524288) { pw1b[i] = f2b(pw1_w[i]); return; }
    i -= 524288;
    if (i < 262144) { pw2b[i] = f2b(pw2_w[i]); return; }
    i -= 262144;
    if (i < 1048576) { posb[i] = (i < 2047*512) ? f2b(pos_emb[i]) : (u16)0; return; }
    i -= 1048576;
    if (i < 15872) { int kk = i >> 9, d = i & 511; wt[i] = dw_w[d*31+kk]; }
}

// ================= conv-module elementwise =================
__global__ __launch_bounds__(256) void glu_kernel(const float* __restrict__ in, u16* __restrict__ out)
{
    int idx = blockIdx.x*256 + threadIdx.x;
    int r = idx >> 9, c = idx & 511;
    float a  = in[(size_t)r*1024 + c];
    float gg = in[(size_t)r*1024 + 512 + c];
    out[idx] = f2b(a * sigmoidf_(gg));
}

// depthwise conv K=31: each thread = one d, 8 consecutive t (register sliding window)
__global__ __launch_bounds__(256) void dwconv_kernel(const u16* __restrict__ y,
    const float* __restrict__ wt, const float* __restrict__ bias, float* __restrict__ z)
{
    int d  = blockIdx.x*256 + threadIdx.x;
    int c  = blockIdx.y;
    int b  = c >> 7;
    int t0 = (c & 127) << 3;
    const u16* yb = y + (size_t)b*TT*DD + d;
    float wv[31];
    #pragma unroll
    for (int kk=0;kk<31;kk++) wv[kk] = wt[kk*512 + d];
    float xv[38];
    #pragma unroll
    for (int e=0;e<38;e++){
        int tp = t0 - 15 + e;
        xv[e] = (tp>=0 && tp<TT) ? b2f(yb[(size_t)tp*DD]) : 0.0f;
    }
    float bsv = bias[d];
    #pragma unroll
    for (int j=0;j<8;j++){
        float s = bsv;
        #pragma unroll
        for (int kk=0;kk<31;kk++) s = fmaf(xv[j+kk], wv[kk], s);
        z[(size_t)(b*TT+t0+j)*DD + d] = s;
    }
}

__global__ __launch_bounds__(256) void bn_reduce_kernel(const float* __restrict__ z, float* __restrict__ stats)
{
    int c = blockIdx.x, t = threadIdx.x;
    float s=0.f, q=0.f;
    for (int r=t; r<NTOK; r+=256){
        float vv = z[(size_t)r*DD + c];
        s += vv; q += vv*vv;
    }
    __shared__ float rs[256], rq[256];
    rs[t]=s; rq[t]=q; __syncthreads();
    for (int st=128; st>0; st>>=1){
        if (t<st){ rs[t]+=rs[t+st]; rq[t]+=rq[t+st]; }
        __syncthreads();
    }
    if (t==0){ stats[c]=rs[0]; stats[DD+c]=rq[0]; }
}

__global__ __launch_bounds__(256) void bn_apply_kernel(const float* __restrict__ z,
    const float* __restrict__ stats, const float* __restrict__ g, const float* __restrict__ b,
    u16* __restrict__ out)
{
    int idx = blockIdx.x*256 + threadIdx.x;
    int c = idx & (DD-1);
    float m   = stats[c]*(1.0f/NTOK);
    float var = stats[DD+c]*(1.0f/NTOK) - m*m;
    float vv  = (z[idx]-m)*rsqrtf(var+EPSF)*g[c] + b[c];
    out[idx]  = f2b(vv*sigmoidf_(vv));
}

extern "C" void kernel_launch(void* const* d_in, const int* in_sizes, int n_in,
                              void* d_out, int out_size, void* d_ws, size_t ws_size,
                              hipStream_t stream)
{
    const float* x       = (const float*)d_in[0];
    const float* pos_emb = (const float*)d_in[1];
    const float* ln1_g=(const float*)d_in[2],  *ln1_b=(const float*)d_in[3];
    const float* ln2_g=(const float*)d_in[4],  *ln2_b=(const float*)d_in[5];
    const float* ln3_g=(const float*)d_in[6],  *ln3_b=(const float*)d_in[7];
    const float* ln4_g=(const float*)d_in[8],  *ln4_b=(const float*)d_in[9];
    const float* ln5_g=(const float*)d_in[10], *ln5_b=(const float*)d_in[11];
    const float* ff1_w1=(const float*)d_in[12], *ff1_b1=(const float*)d_in[13];
    const float* ff1_w2=(const float*)d_in[14], *ff1_b2=(const float*)d_in[15];
    const float* wq=(const float*)d_in[16], *bq=(const float*)d_in[17];
    const float* wk=(const float*)d_in[18], *bk=(const float*)d_in[19];
    const float* wv=(const float*)d_in[20], *bv=(const float*)d_in[21];
    const float* wp=(const float*)d_in[22];
    const float* wo=(const float*)d_in[23], *bo=(const float*)d_in[24];
    const float* pos_u=(const float*)d_in[25], *pos_v=(const float*)d_in[26];
    const float* pw1_w=(const float*)d_in[27], *pw1_b=(const float*)d_in[28];
    const float* dw_w=(const float*)d_in[29],  *dw_b=(const float*)d_in[30];
    const float* bn_g=(const float*)d_in[31],  *bn_b=(const float*)d_in[32];
    const float* pw2_w=(const float*)d_in[33], *pw2_b=(const float*)d_in[34];
    const float* ff2_w1=(const float*)d_in[35], *ff2_b1=(const float*)d_in[36];
    const float* ff2_w2=(const float*)d_in[37], *ff2_b2=(const float*)d_in[38];

    char* W = (char*)d_ws;
    float* h    = (float*)(W);                  // 8 MB f32
    u16*  xn    = (u16*) (W + (size_t) 8*MB);   // 4 MB (ln out / attn out / glu out)
    u16*  wall  = (u16*) (W + (size_t)12*MB);   // 16 MB all prepped weights
    u16*  qub   = (u16*) (W + (size_t)28*MB);
    u16*  qvb   = (u16*) (W + (size_t)32*MB);
    u16*  kb    = (u16*) (W + (size_t)36*MB);
    u16*  vt    = (u16*) (W + (size_t)40*MB);   // (B,H,DK,T)
    u16*  pproj = (u16*) (W + (size_t)44*MB);   // 2048x512
    char* big   = W + (size_t)48*MB;            // shared region
    u16*  ffh   = (u16*)big;                    // 16 MB FFN hidden
    float* t2   = (float*)big;                  // 16 MB conv pw1 out
    float* t3   = (float*)(big + (size_t)16*MB);// 8 MB dwconv out
    float* stats= (float*)(W + (size_t)112*MB); // 4 KB
    float* wt   = stats + 4096;                 // 63.5 KB (31,512) f32

    u16* ff1w1T = wall;
    u16* ff1w2T = wall + 1048576;
    u16* wqT    = wall + 2097152;
    u16* wkT    = wall + 2359296;
    u16* wvT    = wall + 2621440;
    u16* wpT    = wall + 2883584;
    u16* woT    = wall + 3145728;
    u16* ff2w1T = wall + 3407872;
    u16* ff2w2T = wall + 4456448;
    u16* pw1b   = wall + 5505024;
    u16* pw2b   = wall + 6029312;
    u16* posb   = wall + 6291456;

    dim3 blk(256);
    const long S0 = 0;

    // ---------------- weight prep (2 launches) ----------------
    Prep9 P;
    P.s[0]=ff1_w1; P.d[0]=ff1w1T; P.R[0]=512;  P.C[0]=2048;
    P.s[1]=ff1_w2; P.d[1]=ff1w2T; P.R[1]=2048; P.C[1]=512;
    P.s[2]=wq;     P.d[2]=wqT;    P.R[2]=512;  P.C[2]=512;
    P.s[3]=wk;     P.d[3]=wkT;    P.R[3]=512;  P.C[3]=512;
    P.s[4]=wv;     P.d[4]=wvT;    P.R[4]=512;  P.C[4]=512;
    P.s[5]=wp;     P.d[5]=wpT;    P.R[5]=512;  P.C[5]=512;
    P.s[6]=wo;     P.d[6]=woT;    P.R[6]=512;  P.C[6]=512;
    P.s[7]=ff2_w1; P.d[7]=ff2w1T; P.R[7]=512;  P.C[7]=2048;
    P.s[8]=ff2_w2; P.d[8]=ff2w2T; P.R[8]=2048; P.C[8]=512;
    int tc[9] = {1024,1024,256,256,256,256,256,1024,1024};
    P.t0[0]=0; for (int e=0;e<9;e++) P.t0[e+1]=P.t0[e]+tc[e];
    prep_transpose<<<dim3(5376), blk, 0, stream>>>(P);
    prep_convert<<<dim3(7230), blk, 0, stream>>>(pw1_w, pw2_w, pos_emb, dw_w,
                                                 pw1b, pw2b, posb, wt);

    // ---------------- FFN1: h = x + 0.5*ffn(ln1(x)) ----------------
    ln_kernel<1><<<dim3(NTOK), blk, 0, stream>>>(x, ln1_g, ln1_b, xn);
    bgemm<1><<<dim3(32,32,1), blk, 0, stream>>>(xn,512,S0,S0, ff1w1T,512,S0,S0,
        ffh,2048,S0,S0, 4096,2048,512, ff1_b1,1,1.f, nullptr,nullptr,nullptr,nullptr);
    bgemm<0><<<dim3(8,32,1), blk, 0, stream>>>(ffh,2048,S0,S0, ff1w2T,2048,S0,S0,
        h,512,S0,S0, 4096,512,2048, ff1_b2,0,0.5f, x,nullptr,nullptr,nullptr);

    // ---------------- Attention: h = h + attn(ln2(h)) ----------------
    ln_kernel<1><<<dim3(NTOK), blk, 0, stream>>>(h, ln2_g, ln2_b, xn);
    bgemm<3><<<dim3(8,32,1), blk, 0, stream>>>(xn,512,S0,S0, wqT,512,S0,S0,
        qub,512,S0,S0, 4096,512,512, bq,0,1.f, nullptr,pos_u,pos_v,qvb);
    bgemm<1><<<dim3(8,32,1), blk, 0, stream>>>(xn,512,S0,S0, wkT,512,S0,S0,
        kb,512,S0,S0, 4096,512,512, bk,0,1.f, nullptr,nullptr,nullptr,nullptr);
    bgemm<2><<<dim3(8,32,1), blk, 0, stream>>>(xn,512,S0,S0, wvT,512,S0,S0,
        vt,512,S0,S0, 4096,512,512, bv,0,1.f, nullptr,nullptr,nullptr,nullptr);
    bgemm<1><<<dim3(8,16,1), blk, 0, stream>>>(posb,512,S0,S0, wpT,512,S0,S0,
        pproj,512,S0,S0, 2048,512,512, nullptr,0,1.f, nullptr,nullptr,nullptr,nullptr);

    attn_fused<<<dim3(16,32), blk, 0, stream>>>(qub, qvb, kb, vt, pproj, xn);

    bgemm<0><<<dim3(8,32,1), blk, 0, stream>>>(xn,512,S0,S0, woT,512,S0,S0,
        h,512,S0,S0, 4096,512,512, bo,0,1.f, h,nullptr,nullptr,nullptr);

    // ---------------- Conv module ----------------
    ln_kernel<1><<<dim3(NTOK), blk, 0, stream>>>(h, ln3_g, ln3_b, xn);
    bgemm<0><<<dim3(16,32,1), blk, 0, stream>>>(xn,512,S0,S0, pw1b,512,S0,S0,
        t2,1024,S0,S0, 4096,1024,512, pw1_b,0,1.f, nullptr,nullptr,nullptr,nullptr);
    glu_kernel<<<dim3(NTOK*DD/256), blk, 0, stream>>>(t2, xn);
    dwconv_kernel<<<dim3(2,512), blk, 0, stream>>>(xn, wt, dw_b, t3);
    bn_reduce_kernel<<<dim3(DD), blk, 0, stream>>>(t3, stats);
    bn_apply_kernel<<<dim3(NTOK*DD/256), blk, 0, stream>>>(t3, stats, bn_g, bn_b, xn);
    bgemm<0><<<dim3(8,32,1), blk, 0, stream>>>(xn,512,S0,S0, pw2b,512,S0,S0,
        h,512,S0,S0, 4096,512,512, pw2_b,0,1.f, h,nullptr,nullptr,nullptr);

    // ---------------- FFN2 ----------------
    ln_kernel<1><<<dim3(NTOK), blk, 0, stream>>>(h, ln4_g, ln4_b, xn);
    bgemm<1><<<dim3(32,32,1), blk, 0, stream>>>(xn,512,S0,S0, ff2w1T,512,S0,S0,
        ffh,2048,S0,S0, 4096,2048,512, ff2_b1,1,1.f, nullptr,nullptr,nullptr,nullptr);
    bgemm<0><<<dim3(8,32,1), blk, 0, stream>>>(ffh,2048,S0,S0, ff2w2T,2048,S0,S0,
        h,512,S0,S0, 4096,512,2048, ff2_b2,0,0.5f, h,nullptr,nullptr,nullptr);

    // ---------------- Final LN ----------------
    ln_kernel<0><<<dim3(NTOK), blk, 0, stream>>>(h, ln5_g, ln5_b, (float*)d_out);
}